// Round 5
// baseline (584.817 us; speedup 1.0000x reference)
//
#include <hip/hip_runtime.h>

#define NN 50000
#define NE 800000
#define IND 64
#define HID 128
#define OUTD 64

// ---------------- CSR build: histogram ----------------
__global__ void hist_kernel(const int* __restrict__ dst, int* __restrict__ cnt) {
    int e = blockIdx.x * blockDim.x + threadIdx.x;
    if (e < NE) atomicAdd(&cnt[dst[e]], 1);
}

// ---------------- 3-phase exclusive scan over NN counts ----------------
__global__ void scan1_kernel(const int* __restrict__ cnt, int* __restrict__ excl,
                             int* __restrict__ bsum) {
    __shared__ int tmp[256];
    int tid = threadIdx.x;
    int i = blockIdx.x * 256 + tid;
    int v = (i < NN) ? cnt[i] : 0;
    tmp[tid] = v;
    __syncthreads();
    for (int off = 1; off < 256; off <<= 1) {
        int t = (tid >= off) ? tmp[tid - off] : 0;
        __syncthreads();
        tmp[tid] += t;
        __syncthreads();
    }
    if (i < NN) excl[i] = tmp[tid] - v;   // exclusive
    if (tid == 255) bsum[blockIdx.x] = tmp[255];
}

__global__ void scan2_kernel(int* __restrict__ bsum, int* __restrict__ boff, int nb) {
    __shared__ int tmp[256];
    int tid = threadIdx.x;
    int v = (tid < nb) ? bsum[tid] : 0;
    tmp[tid] = v;
    __syncthreads();
    for (int off = 1; off < 256; off <<= 1) {
        int t = (tid >= off) ? tmp[tid - off] : 0;
        __syncthreads();
        tmp[tid] += t;
        __syncthreads();
    }
    if (tid < nb) boff[tid] = tmp[tid] - v;
}

// in-place: start = excl + boff[block]; next (cursor copy) = same
__global__ void scan3_kernel(int* __restrict__ excl, const int* __restrict__ boff,
                             int* __restrict__ next) {
    int i = blockIdx.x * 256 + threadIdx.x;
    if (i < NN) {
        int s = excl[i] + boff[blockIdx.x];
        excl[i] = s;    // becomes start[]
        next[i] = s;    // scatter cursor
    }
}

// ---------------- scatter edges into CSR order ----------------
__global__ void scatter_kernel(const int* __restrict__ src, const int* __restrict__ dst,
                               int* __restrict__ next, int* __restrict__ perm) {
    int e = blockIdx.x * blockDim.x + threadIdx.x;
    if (e < NE) {
        int pos = atomicAdd(&next[dst[e]], 1);
        perm[pos] = src[e];
    }
}

// ---------------- gather-aggregate (mean): one wave per node ----------------
// 64 lanes: 4 edge-subgroups (g=lane>>4) x 16 float4 slots (q=lane&15).
// feat row s lives at feat4[s*fstride + foff .. +16); out row n at out4[n*ostride + ooff ..).
// ACCUM=true: out += mean (out already holds the self term; wave owns its node).
template<bool ACCUM>
__global__ __launch_bounds__(256) void agg_gather_kernel(
    const float4* __restrict__ feat4, int fstride, int foff,
    const int* __restrict__ start, const int* __restrict__ perm,
    float4* __restrict__ out4, int ostride, int ooff)
{
    int wave = (blockIdx.x * blockDim.x + threadIdx.x) >> 6;
    if (wave >= NN) return;
    int lane = threadIdx.x & 63;
    int g = lane >> 4;
    int q = lane & 15;
    int rs = start[wave];
    int re = (wave == NN - 1) ? NE : start[wave + 1];
    int cnt = re - rs;
    float4 acc = {0.f, 0.f, 0.f, 0.f};
    for (int i = rs + g; i < re; i += 4) {
        int s = perm[i];
        float4 v = feat4[(size_t)s * fstride + foff + q];
        acc.x += v.x; acc.y += v.y; acc.z += v.z; acc.w += v.w;
    }
    // reduce the 4 subgroups (lane bits 4,5)
    acc.x += __shfl_xor(acc.x, 16, 64); acc.y += __shfl_xor(acc.y, 16, 64);
    acc.z += __shfl_xor(acc.z, 16, 64); acc.w += __shfl_xor(acc.w, 16, 64);
    acc.x += __shfl_xor(acc.x, 32, 64); acc.y += __shfl_xor(acc.y, 32, 64);
    acc.z += __shfl_xor(acc.z, 32, 64); acc.w += __shfl_xor(acc.w, 32, 64);
    if (g == 0) {
        float inv = (cnt > 0) ? (1.0f / (float)cnt) : 0.f;
        float4 r = {acc.x * inv, acc.y * inv, acc.z * inv, acc.w * inv};
        size_t oidx = (size_t)wave * ostride + ooff + q;
        if (ACCUM) {
            float4 o = out4[oidx];
            r.x += o.x; r.y += o.y; r.z += o.z; r.w += o.w;
        }
        out4[oidx] = r;
    }
}

// ---------------- conv1: hpre = agg@W1l + b1 + x@W1r ; BN partial stats ----------------
// agg[n] lives in hpre[n][64..128). 8-node tiles, float4 LDS broadcasts.
__global__ __launch_bounds__(256, 3) void conv1_kernel(
    const float* __restrict__ x,
    const float* __restrict__ W1l, const float* __restrict__ b1,
    const float* __restrict__ W1r,
    float* __restrict__ hpre, float* __restrict__ sums, float* __restrict__ sumsq)
{
    __shared__ float4 aggv[8][16];
    __shared__ float4 xv[8][16];
    int tid = threadIdx.x;
    int j = tid & 127;
    int half = tid >> 7;
    float4 wl[16], wr[16];
#pragma unroll
    for (int k4 = 0; k4 < 16; k4++) {
        wl[k4].x = W1l[(4 * k4 + 0) * HID + j];
        wl[k4].y = W1l[(4 * k4 + 1) * HID + j];
        wl[k4].z = W1l[(4 * k4 + 2) * HID + j];
        wl[k4].w = W1l[(4 * k4 + 3) * HID + j];
        wr[k4].x = W1r[(4 * k4 + 0) * HID + j];
        wr[k4].y = W1r[(4 * k4 + 1) * HID + j];
        wr[k4].z = W1r[(4 * k4 + 2) * HID + j];
        wr[k4].w = W1r[(4 * k4 + 3) * HID + j];
    }
    float bj = b1[j];
    const float4* x4 = (const float4*)x;
    const float4* hp4 = (const float4*)hpre;
    // staging role
    int sarr = tid >> 7;            // 0: agg, 1: x
    int snode = (tid >> 4) & 7;
    int sq = tid & 15;
    float lsum = 0.f, lsq = 0.f;
    for (int grp = blockIdx.x; grp < NN / 8; grp += gridDim.x) {
        int n0 = grp * 8;
        __syncthreads();
        if (sarr == 0) aggv[snode][sq] = hp4[(size_t)(n0 + snode) * 32 + 16 + sq];
        else           xv[snode][sq]   = x4[(size_t)(n0 + snode) * 16 + sq];
        __syncthreads();
#pragma unroll
        for (int m = 0; m < 4; m++) {
            int ln = m * 2 + half;
            float acc = bj;
#pragma unroll
            for (int k4 = 0; k4 < 16; k4++) {
                float4 a = aggv[ln][k4];
                float4 b = xv[ln][k4];
                acc += a.x * wl[k4].x + a.y * wl[k4].y + a.z * wl[k4].z + a.w * wl[k4].w;
                acc += b.x * wr[k4].x + b.y * wr[k4].y + b.z * wr[k4].z + b.w * wr[k4].w;
            }
            hpre[(size_t)(n0 + ln) * HID + j] = acc;
            lsum += acc;
            lsq += acc * acc;
        }
    }
    atomicAdd(&sums[j], lsum);
    atomicAdd(&sumsq[j], lsq);
}

// ---------------- BN stats -> scale/shift ----------------
__global__ void bnstat_kernel(const float* __restrict__ sums, const float* __restrict__ sumsq,
                              const float* __restrict__ gamma, const float* __restrict__ beta,
                              float* __restrict__ scale, float* __restrict__ shift) {
    int c = threadIdx.x;
    if (c < HID) {
        float inv_n = 1.0f / (float)NN;
        float mu = sums[c] * inv_n;
        float var = sumsq[c] * inv_n - mu * mu;
        float s = gamma[c] * rsqrtf(var + 1e-5f);
        scale[c] = s;
        shift[c] = beta[c] - mu * s;
    }
}

// ---------------- conv2 pre: h = relu(BN(hpre)); p = h@W2l -> hpre[n][64..); self -> out ----
__global__ __launch_bounds__(256, 3) void conv2pre_kernel(
    float* __restrict__ hpre, const float* __restrict__ scale, const float* __restrict__ shift,
    const float* __restrict__ W2l, const float* __restrict__ b2, const float* __restrict__ W2r,
    float* __restrict__ outp)
{
    __shared__ float4 hv[8][32];
    __shared__ float4 sc4[32];
    __shared__ float4 sh4[32];
    int tid = threadIdx.x;
    int j = tid & 127;
    int half = tid >> 7;
    int jj = j & 63;
    const float* W = (j < 64) ? W2l : W2r;
    float4 w4[32];
#pragma unroll
    for (int k4 = 0; k4 < 32; k4++) {
        w4[k4].x = W[(4 * k4 + 0) * OUTD + jj];
        w4[k4].y = W[(4 * k4 + 1) * OUTD + jj];
        w4[k4].z = W[(4 * k4 + 2) * OUTD + jj];
        w4[k4].w = W[(4 * k4 + 3) * OUTD + jj];
    }
    float bj = (j >= 64) ? b2[jj] : 0.f;
    if (tid < 32) sc4[tid] = ((const float4*)scale)[tid];
    else if (tid < 64) sh4[tid - 32] = ((const float4*)shift)[tid - 32];
    float4* hp4 = (float4*)hpre;
    int snode = tid >> 5;
    int sq = tid & 31;
    for (int grp = blockIdx.x; grp < NN / 8; grp += gridDim.x) {
        int n0 = grp * 8;
        __syncthreads();
        {
            float4 v = hp4[(size_t)(n0 + snode) * 32 + sq];
            float4 s = sc4[sq], t = sh4[sq];
            v.x = v.x * s.x + t.x; v.y = v.y * s.y + t.y;
            v.z = v.z * s.z + t.z; v.w = v.w * s.w + t.w;
            v.x = v.x > 0.f ? v.x : 0.f; v.y = v.y > 0.f ? v.y : 0.f;
            v.z = v.z > 0.f ? v.z : 0.f; v.w = v.w > 0.f ? v.w : 0.f;
            hv[snode][sq] = v;
        }
        __syncthreads();
#pragma unroll
        for (int m = 0; m < 4; m++) {
            int ln = m * 2 + half;
            float acc = bj;
#pragma unroll
            for (int k4 = 0; k4 < 32; k4++) {
                float4 h = hv[ln][k4];
                acc += h.x * w4[k4].x + h.y * w4[k4].y + h.z * w4[k4].z + h.w * w4[k4].w;
            }
            int n = n0 + ln;
            if (j < 64) hpre[(size_t)n * HID + 64 + j] = acc;   // p (row already staged)
            else        outp[(size_t)n * 64 + jj] = acc;        // self term
        }
    }
}

extern "C" void kernel_launch(void* const* d_in, const int* in_sizes, int n_in,
                              void* d_out, int out_size, void* d_ws, size_t ws_size,
                              hipStream_t stream) {
    const float* x     = (const float*)d_in[0];
    const int*   ei    = (const int*)d_in[1];
    const float* W1l   = (const float*)d_in[2];
    const float* b1    = (const float*)d_in[3];
    const float* W1r   = (const float*)d_in[4];
    const float* gamma = (const float*)d_in[5];
    const float* beta  = (const float*)d_in[6];
    const float* W2l   = (const float*)d_in[7];
    const float* b2    = (const float*)d_in[8];
    const float* W2r   = (const float*)d_in[9];
    float* out = (float*)d_out;

    // workspace layout (total ~29.2 MB)
    int*   cnt   = (int*)d_ws;                 // NN (reused as scatter cursor)
    int*   startp= cnt + NN;                   // NN (excl scan -> start, in place)
    int*   bsum  = cnt + 2 * NN;               // 256
    int*   boff  = bsum + 256;                 // 256
    int*   perm  = boff + 256;                 // NE
    float* hpre  = (float*)(perm + NE);        // NN*128; col [64..128) doubles as agg / p
    float* sums  = hpre + (size_t)NN * HID;    // 128
    float* sumsq = sums + 128;                 // 128
    float* scale = sums + 256;                 // 128
    float* shift = sums + 384;                 // 128

    const int* srcp = ei;
    const int* dstp = ei + NE;

    hipMemsetAsync(cnt, 0, sizeof(int) * NN, stream);
    hipMemsetAsync(sums, 0, sizeof(float) * 256, stream);

    const int EB = (NE + 255) / 256;           // 3125
    const int SB = (NN + 255) / 256;           // 196
    const int GB = (NN * 64 + 255) / 256;      // 12500 (one wave per node)
    const int CB = 2048;                       // conv grid

    hist_kernel<<<EB, 256, 0, stream>>>(dstp, cnt);
    scan1_kernel<<<SB, 256, 0, stream>>>(cnt, startp, bsum);
    scan2_kernel<<<1, 256, 0, stream>>>(bsum, boff, SB);
    scan3_kernel<<<SB, 256, 0, stream>>>(startp, boff, cnt);   // cnt becomes cursor
    scatter_kernel<<<EB, 256, 0, stream>>>(srcp, dstp, cnt, perm);

    // agg1: x (stride 16 f4, off 0) -> hpre cols [64..) (stride 32 f4, off 16)
    agg_gather_kernel<false><<<GB, 256, 0, stream>>>(
        (const float4*)x, 16, 0, startp, perm, (float4*)hpre, 32, 16);
    conv1_kernel<<<CB, 256, 0, stream>>>(x, W1l, b1, W1r, hpre, sums, sumsq);
    bnstat_kernel<<<1, 128, 0, stream>>>(sums, sumsq, gamma, beta, scale, shift);
    conv2pre_kernel<<<CB, 256, 0, stream>>>(hpre, scale, shift, W2l, b2, W2r, out);
    // agg2: p = hpre cols [64..) (stride 32, off 16) -> out (stride 16, off 0), accumulate
    agg_gather_kernel<true><<<GB, 256, 0, stream>>>(
        (const float4*)hpre, 32, 16, startp, perm, (float4*)out, 16, 0);
}

// Round 6
// 404.506 us; speedup vs baseline: 1.4458x; 1.4458x over previous
//
#include <hip/hip_runtime.h>

#define NN 50000
#define NE 800000
#define IND 64
#define HID 128
#define OUTD 64

// ---------------- CSR build: histogram ----------------
__global__ void hist_kernel(const int* __restrict__ dst, int* __restrict__ cnt) {
    int e = blockIdx.x * blockDim.x + threadIdx.x;
    if (e < NE) atomicAdd(&cnt[dst[e]], 1);
}

// ---------------- 3-phase exclusive scan over NN counts ----------------
__global__ void scan1_kernel(const int* __restrict__ cnt, int* __restrict__ excl,
                             int* __restrict__ bsum) {
    __shared__ int tmp[256];
    int tid = threadIdx.x;
    int i = blockIdx.x * 256 + tid;
    int v = (i < NN) ? cnt[i] : 0;
    tmp[tid] = v;
    __syncthreads();
    for (int off = 1; off < 256; off <<= 1) {
        int t = (tid >= off) ? tmp[tid - off] : 0;
        __syncthreads();
        tmp[tid] += t;
        __syncthreads();
    }
    if (i < NN) excl[i] = tmp[tid] - v;   // exclusive
    if (tid == 255) bsum[blockIdx.x] = tmp[255];
}

__global__ void scan2_kernel(int* __restrict__ bsum, int* __restrict__ boff, int nb) {
    __shared__ int tmp[256];
    int tid = threadIdx.x;
    int v = (tid < nb) ? bsum[tid] : 0;
    tmp[tid] = v;
    __syncthreads();
    for (int off = 1; off < 256; off <<= 1) {
        int t = (tid >= off) ? tmp[tid - off] : 0;
        __syncthreads();
        tmp[tid] += t;
        __syncthreads();
    }
    if (tid < nb) boff[tid] = tmp[tid] - v;
}

// in-place: start = excl + boff[block]; next (cursor copy) = same
__global__ void scan3_kernel(int* __restrict__ excl, const int* __restrict__ boff,
                             int* __restrict__ next) {
    int i = blockIdx.x * 256 + threadIdx.x;
    if (i < NN) {
        int s = excl[i] + boff[blockIdx.x];
        excl[i] = s;    // becomes start[]
        next[i] = s;    // scatter cursor
    }
}

// ---------------- scatter edges into CSR order ----------------
__global__ void scatter_kernel(const int* __restrict__ src, const int* __restrict__ dst,
                               int* __restrict__ next, int* __restrict__ perm) {
    int e = blockIdx.x * blockDim.x + threadIdx.x;
    if (e < NE) {
        int pos = atomicAdd(&next[dst[e]], 1);
        perm[pos] = src[e];
    }
}

// ---------------- gather-aggregate (mean): one wave per node ----------------
template<bool ACCUM>
__global__ __launch_bounds__(256) void agg_gather_kernel(
    const float4* __restrict__ feat4, int fstride, int foff,
    const int* __restrict__ start, const int* __restrict__ perm,
    float4* __restrict__ out4, int ostride, int ooff)
{
    int wave = (blockIdx.x * blockDim.x + threadIdx.x) >> 6;
    if (wave >= NN) return;
    int lane = threadIdx.x & 63;
    int g = lane >> 4;
    int q = lane & 15;
    int rs = start[wave];
    int re = (wave == NN - 1) ? NE : start[wave + 1];
    int cnt = re - rs;
    float4 acc = {0.f, 0.f, 0.f, 0.f};
    for (int i = rs + g; i < re; i += 4) {
        int s = perm[i];
        float4 v = feat4[(size_t)s * fstride + foff + q];
        acc.x += v.x; acc.y += v.y; acc.z += v.z; acc.w += v.w;
    }
    acc.x += __shfl_xor(acc.x, 16, 64); acc.y += __shfl_xor(acc.y, 16, 64);
    acc.z += __shfl_xor(acc.z, 16, 64); acc.w += __shfl_xor(acc.w, 16, 64);
    acc.x += __shfl_xor(acc.x, 32, 64); acc.y += __shfl_xor(acc.y, 32, 64);
    acc.z += __shfl_xor(acc.z, 32, 64); acc.w += __shfl_xor(acc.w, 32, 64);
    if (g == 0) {
        float inv = (cnt > 0) ? (1.0f / (float)cnt) : 0.f;
        float4 r = {acc.x * inv, acc.y * inv, acc.z * inv, acc.w * inv};
        size_t oidx = (size_t)wave * ostride + ooff + q;
        if (ACCUM) {
            float4 o = out4[oidx];
            r.x += o.x; r.y += o.y; r.z += o.z; r.w += o.w;
        }
        out4[oidx] = r;
    }
}

// ---------------- conv1: hpre = agg@W1l + b1 + x@W1r ; BN partial stats ----------------
// K-split: s=0 threads own W1l col j (64 regs) & compute agg-term; s=1 own W1r & x-term.
// Partials combined via LDS. agg[n] lives in hpre[n][64..128), staged before overwrite.
__global__ __launch_bounds__(256) void conv1_kernel(
    const float* __restrict__ x,
    const float* __restrict__ W1l, const float* __restrict__ b1,
    const float* __restrict__ W1r,
    float* __restrict__ hpre, float* __restrict__ sums, float* __restrict__ sumsq)
{
    __shared__ float4 aggv[8][16];
    __shared__ float4 xv[8][16];
    __shared__ float part[8][128];
    int tid = threadIdx.x;
    int j = tid & 127;
    int s = tid >> 7;
    const float* Wcol = s ? W1r : W1l;
    float4 w[16];
#pragma unroll
    for (int k4 = 0; k4 < 16; k4++) {
        w[k4].x = Wcol[(4 * k4 + 0) * HID + j];
        w[k4].y = Wcol[(4 * k4 + 1) * HID + j];
        w[k4].z = Wcol[(4 * k4 + 2) * HID + j];
        w[k4].w = Wcol[(4 * k4 + 3) * HID + j];
    }
    float bj = b1[j];
    const float4* x4 = (const float4*)x;
    const float4* hp4 = (const float4*)hpre;
    int snode = (tid >> 4) & 7;
    int sq = tid & 15;
    float lsum = 0.f, lsq = 0.f;
    for (int grp = blockIdx.x; grp < NN / 8; grp += gridDim.x) {
        int n0 = grp * 8;
        __syncthreads();
        if (s == 0) aggv[snode][sq] = hp4[(size_t)(n0 + snode) * 32 + 16 + sq];
        else        xv[snode][sq]   = x4[(size_t)(n0 + snode) * 16 + sq];
        __syncthreads();
        float acc[8];
#pragma unroll
        for (int m = 0; m < 8; m++) acc[m] = 0.f;
        if (s == 0) {
#pragma unroll
            for (int k4 = 0; k4 < 16; k4++) {
                float4 wv = w[k4];
#pragma unroll
                for (int m = 0; m < 8; m++) {
                    float4 f = aggv[m][k4];
                    acc[m] += f.x * wv.x + f.y * wv.y + f.z * wv.z + f.w * wv.w;
                }
            }
        } else {
#pragma unroll
            for (int k4 = 0; k4 < 16; k4++) {
                float4 wv = w[k4];
#pragma unroll
                for (int m = 0; m < 8; m++) {
                    float4 f = xv[m][k4];
                    acc[m] += f.x * wv.x + f.y * wv.y + f.z * wv.z + f.w * wv.w;
                }
            }
#pragma unroll
            for (int m = 0; m < 8; m++) part[m][j] = acc[m];
        }
        __syncthreads();
        if (s == 0) {
#pragma unroll
            for (int m = 0; m < 8; m++) {
                float v = acc[m] + part[m][j] + bj;
                hpre[(size_t)(n0 + m) * HID + j] = v;
                lsum += v;
                lsq += v * v;
            }
        }
    }
    if (s == 0) {
        atomicAdd(&sums[j], lsum);
        atomicAdd(&sumsq[j], lsq);
    }
}

// ---------------- BN stats -> scale/shift ----------------
__global__ void bnstat_kernel(const float* __restrict__ sums, const float* __restrict__ sumsq,
                              const float* __restrict__ gamma, const float* __restrict__ beta,
                              float* __restrict__ scale, float* __restrict__ shift) {
    int c = threadIdx.x;
    if (c < HID) {
        float inv_n = 1.0f / (float)NN;
        float mu = sums[c] * inv_n;
        float var = sumsq[c] * inv_n - mu * mu;
        float s = gamma[c] * rsqrtf(var + 1e-5f);
        scale[c] = s;
        shift[c] = beta[c] - mu * s;
    }
}

// ---------------- conv2 pre: h = relu(BN(hpre)); p = h@W2l -> hpre[n][64..); self -> out ----
// K-split: thread (j,s): j<64 -> W2l col j (p), j>=64 -> W2r col j-64 (self); s = K-half.
__global__ __launch_bounds__(256) void conv2pre_kernel(
    float* __restrict__ hpre, const float* __restrict__ scale, const float* __restrict__ shift,
    const float* __restrict__ W2l, const float* __restrict__ b2, const float* __restrict__ W2r,
    float* __restrict__ outp)
{
    __shared__ float4 hv[8][32];
    __shared__ float part[8][128];
    __shared__ float4 sc4[32];
    __shared__ float4 sh4[32];
    int tid = threadIdx.x;
    int j = tid & 127;
    int s = tid >> 7;
    int jj = j & 63;
    const float* W = (j < 64) ? W2l : W2r;
    float4 w[16];
#pragma unroll
    for (int k4 = 0; k4 < 16; k4++) {
        int k = s * 64 + 4 * k4;
        w[k4].x = W[(k + 0) * OUTD + jj];
        w[k4].y = W[(k + 1) * OUTD + jj];
        w[k4].z = W[(k + 2) * OUTD + jj];
        w[k4].w = W[(k + 3) * OUTD + jj];
    }
    float bj = b2[jj];
    if (tid < 32) sc4[tid] = ((const float4*)scale)[tid];
    else if (tid < 64) sh4[tid - 32] = ((const float4*)shift)[tid - 32];
    float4* hp4 = (float4*)hpre;
    int snode = tid >> 5;
    int sq = tid & 31;
    for (int grp = blockIdx.x; grp < NN / 8; grp += gridDim.x) {
        int n0 = grp * 8;
        __syncthreads();
        {
            float4 v = hp4[(size_t)(n0 + snode) * 32 + sq];
            float4 sc = sc4[sq], sh = sh4[sq];
            v.x = v.x * sc.x + sh.x; v.y = v.y * sc.y + sh.y;
            v.z = v.z * sc.z + sh.z; v.w = v.w * sc.w + sh.w;
            v.x = v.x > 0.f ? v.x : 0.f; v.y = v.y > 0.f ? v.y : 0.f;
            v.z = v.z > 0.f ? v.z : 0.f; v.w = v.w > 0.f ? v.w : 0.f;
            hv[snode][sq] = v;
        }
        __syncthreads();
        float acc[8];
#pragma unroll
        for (int m = 0; m < 8; m++) acc[m] = 0.f;
#pragma unroll
        for (int k4 = 0; k4 < 16; k4++) {
            float4 wv = w[k4];
            int kk = s * 16 + k4;
#pragma unroll
            for (int m = 0; m < 8; m++) {
                float4 f = hv[m][kk];
                acc[m] += f.x * wv.x + f.y * wv.y + f.z * wv.z + f.w * wv.w;
            }
        }
        if (s == 1) {
#pragma unroll
            for (int m = 0; m < 8; m++) part[m][j] = acc[m];
        }
        __syncthreads();
        if (s == 0) {
#pragma unroll
            for (int m = 0; m < 8; m++) {
                float v = acc[m] + part[m][j];
                int n = n0 + m;
                if (j < 64) hpre[(size_t)n * HID + 64 + j] = v;       // p
                else        outp[(size_t)n * 64 + jj] = v + bj;       // self term
            }
        }
    }
}

extern "C" void kernel_launch(void* const* d_in, const int* in_sizes, int n_in,
                              void* d_out, int out_size, void* d_ws, size_t ws_size,
                              hipStream_t stream) {
    const float* x     = (const float*)d_in[0];
    const int*   ei    = (const int*)d_in[1];
    const float* W1l   = (const float*)d_in[2];
    const float* b1    = (const float*)d_in[3];
    const float* W1r   = (const float*)d_in[4];
    const float* gamma = (const float*)d_in[5];
    const float* beta  = (const float*)d_in[6];
    const float* W2l   = (const float*)d_in[7];
    const float* b2    = (const float*)d_in[8];
    const float* W2r   = (const float*)d_in[9];
    float* out = (float*)d_out;

    // workspace layout (total ~29.2 MB)
    int*   cnt   = (int*)d_ws;                 // NN (reused as scatter cursor)
    int*   startp= cnt + NN;                   // NN (excl scan -> start, in place)
    int*   bsum  = cnt + 2 * NN;               // 256
    int*   boff  = bsum + 256;                 // 256
    int*   perm  = boff + 256;                 // NE
    float* hpre  = (float*)(perm + NE);        // NN*128; col [64..128) doubles as agg / p
    float* sums  = hpre + (size_t)NN * HID;    // 128
    float* sumsq = sums + 128;                 // 128
    float* scale = sums + 256;                 // 128
    float* shift = sums + 384;                 // 128

    const int* srcp = ei;
    const int* dstp = ei + NE;

    hipMemsetAsync(cnt, 0, sizeof(int) * NN, stream);
    hipMemsetAsync(sums, 0, sizeof(float) * 256, stream);

    const int EB = (NE + 255) / 256;           // 3125
    const int SB = (NN + 255) / 256;           // 196
    const int GB = (NN * 64 + 255) / 256;      // 12500 (one wave per node)
    const int CB = 2048;                       // conv grid

    hist_kernel<<<EB, 256, 0, stream>>>(dstp, cnt);
    scan1_kernel<<<SB, 256, 0, stream>>>(cnt, startp, bsum);
    scan2_kernel<<<1, 256, 0, stream>>>(bsum, boff, SB);
    scan3_kernel<<<SB, 256, 0, stream>>>(startp, boff, cnt);   // cnt becomes cursor
    scatter_kernel<<<EB, 256, 0, stream>>>(srcp, dstp, cnt, perm);

    // agg1: x (stride 16 f4, off 0) -> hpre cols [64..) (stride 32 f4, off 16)
    agg_gather_kernel<false><<<GB, 256, 0, stream>>>(
        (const float4*)x, 16, 0, startp, perm, (float4*)hpre, 32, 16);
    conv1_kernel<<<CB, 256, 0, stream>>>(x, W1l, b1, W1r, hpre, sums, sumsq);
    bnstat_kernel<<<1, 128, 0, stream>>>(sums, sumsq, gamma, beta, scale, shift);
    conv2pre_kernel<<<CB, 256, 0, stream>>>(hpre, scale, shift, W2l, b2, W2r, out);
    // agg2: p = hpre cols [64..) (stride 32, off 16) -> out (stride 16, off 0), accumulate
    agg_gather_kernel<true><<<GB, 256, 0, stream>>>(
        (const float4*)hpre, 32, 16, startp, perm, (float4*)out, 16, 0);
}

// Round 7
// 306.611 us; speedup vs baseline: 1.9074x; 1.3193x over previous
//
#include <hip/hip_runtime.h>

#define NN 50000
#define NE 800000
#define HID 128
#define OUTD 64

typedef __attribute__((ext_vector_type(8))) short bf16x8;
typedef __attribute__((ext_vector_type(4))) float f32x4;

static __device__ __forceinline__ unsigned short f2bf(float f) {
    unsigned u = __float_as_uint(f);
    unsigned r = (u + 0x7FFFu + ((u >> 16) & 1u)) >> 16;   // RNE
    return (unsigned short)r;
}
static __device__ __forceinline__ float bflo(unsigned u) { return __uint_as_float(u << 16); }
static __device__ __forceinline__ float bfhi(unsigned u) { return __uint_as_float(u & 0xffff0000u); }

// ---------------- CSR build ----------------
__global__ void hist_kernel(const int* __restrict__ dst, int* __restrict__ cnt) {
    int e = blockIdx.x * blockDim.x + threadIdx.x;
    if (e < NE) atomicAdd(&cnt[dst[e]], 1);
}

__global__ void scan1_kernel(const int* __restrict__ cnt, int* __restrict__ excl,
                             int* __restrict__ bsum) {
    __shared__ int tmp[256];
    int tid = threadIdx.x;
    int i = blockIdx.x * 256 + tid;
    int v = (i < NN) ? cnt[i] : 0;
    tmp[tid] = v;
    __syncthreads();
    for (int off = 1; off < 256; off <<= 1) {
        int t = (tid >= off) ? tmp[tid - off] : 0;
        __syncthreads();
        tmp[tid] += t;
        __syncthreads();
    }
    if (i < NN) excl[i] = tmp[tid] - v;
    if (tid == 255) bsum[blockIdx.x] = tmp[255];
}

__global__ void scan2_kernel(int* __restrict__ bsum, int* __restrict__ boff, int nb) {
    __shared__ int tmp[256];
    int tid = threadIdx.x;
    int v = (tid < nb) ? bsum[tid] : 0;
    tmp[tid] = v;
    __syncthreads();
    for (int off = 1; off < 256; off <<= 1) {
        int t = (tid >= off) ? tmp[tid - off] : 0;
        __syncthreads();
        tmp[tid] += t;
        __syncthreads();
    }
    if (tid < nb) boff[tid] = tmp[tid] - v;
}

__global__ void scan3_kernel(int* __restrict__ excl, const int* __restrict__ boff,
                             int* __restrict__ next) {
    int i = blockIdx.x * 256 + threadIdx.x;
    if (i < NN) {
        int s = excl[i] + boff[blockIdx.x];
        excl[i] = s;
        next[i] = s;
    }
}

__global__ void scatter_kernel(const int* __restrict__ src, const int* __restrict__ dst,
                               int* __restrict__ next, int* __restrict__ perm) {
    int e = blockIdx.x * blockDim.x + threadIdx.x;
    if (e < NE) {
        int pos = atomicAdd(&next[dst[e]], 1);
        perm[pos] = src[e];
    }
}

// ---------------- weight prep: BT1[j][k], BT2[j][k] bf16 (transposed, k-contig) --------
__global__ void wprep_kernel(const float* __restrict__ W1l, const float* __restrict__ W1r,
                             const float* __restrict__ W2l, const float* __restrict__ W2r,
                             unsigned short* __restrict__ BT1, unsigned short* __restrict__ BT2) {
    int idx = blockIdx.x * 256 + threadIdx.x;
    if (idx >= 128 * 128) return;
    int j = idx >> 7, k = idx & 127;
    float v1 = (k < 64) ? W1l[k * HID + j] : W1r[(k - 64) * HID + j];
    BT1[j * 128 + k] = f2bf(v1);
    float v2 = (j < 64) ? W2l[k * OUTD + j] : W2r[k * OUTD + (j - 64)];
    BT2[j * 128 + k] = f2bf(v2);
}

// ---------------- x -> bf16 into A1 cols [64:128) ----------------
__global__ void x2bf_kernel(const float* __restrict__ x, unsigned short* __restrict__ A1) {
    int idx = blockIdx.x * 256 + threadIdx.x;   // NN*16 float4 slots
    if (idx >= NN * 16) return;
    int n = idx >> 4, q = idx & 15;
    float4 v = ((const float4*)x)[idx];
    ushort4 o;
    o.x = f2bf(v.x); o.y = f2bf(v.y); o.z = f2bf(v.z); o.w = f2bf(v.w);
    *(ushort4*)(A1 + (size_t)n * 128 + 64 + q * 4) = o;
}

// ---------------- gather-aggregate over bf16 rows (128B/row), one wave per node --------
// MODE 0: store bf16 mean into outb row (stride ostride, offset ooff)   [agg1]
// MODE 1: outf[n*64 + c] += mean (fp32 accumulate, wave owns node)      [agg2]
template<int MODE>
__global__ __launch_bounds__(256) void agg_gather_b(
    const unsigned short* __restrict__ feat, int fstride, int foff,
    const int* __restrict__ start, const int* __restrict__ perm,
    unsigned short* __restrict__ outb, int ostride, int ooff,
    float* __restrict__ outf)
{
    int wave = (blockIdx.x * blockDim.x + threadIdx.x) >> 6;
    if (wave >= NN) return;
    int lane = threadIdx.x & 63;
    int g = lane >> 3;        // 8 edge groups
    int q = lane & 7;         // 8 bf16 per slot
    int rs = start[wave];
    int re = (wave == NN - 1) ? NE : start[wave + 1];
    float acc[8];
#pragma unroll
    for (int t = 0; t < 8; t++) acc[t] = 0.f;
    for (int i = rs + g; i < re; i += 8) {
        int s = perm[i];
        uint4 v = *(const uint4*)(feat + (size_t)s * fstride + foff + q * 8);
        acc[0] += bflo(v.x); acc[1] += bfhi(v.x);
        acc[2] += bflo(v.y); acc[3] += bfhi(v.y);
        acc[4] += bflo(v.z); acc[5] += bfhi(v.z);
        acc[6] += bflo(v.w); acc[7] += bfhi(v.w);
    }
#pragma unroll
    for (int t = 0; t < 8; t++) {
        acc[t] += __shfl_xor(acc[t], 8, 64);
        acc[t] += __shfl_xor(acc[t], 16, 64);
        acc[t] += __shfl_xor(acc[t], 32, 64);
    }
    if (g == 0) {
        int cnt = re - rs;
        float inv = (cnt > 0) ? (1.0f / (float)cnt) : 0.f;
        if (MODE == 0) {
            uint4 o;
            o.x = (unsigned)f2bf(acc[0] * inv) | ((unsigned)f2bf(acc[1] * inv) << 16);
            o.y = (unsigned)f2bf(acc[2] * inv) | ((unsigned)f2bf(acc[3] * inv) << 16);
            o.z = (unsigned)f2bf(acc[4] * inv) | ((unsigned)f2bf(acc[5] * inv) << 16);
            o.w = (unsigned)f2bf(acc[6] * inv) | ((unsigned)f2bf(acc[7] * inv) << 16);
            *(uint4*)(outb + (size_t)wave * ostride + ooff + q * 8) = o;
        } else {
            float4* op = (float4*)(outf + (size_t)wave * 64 + q * 8);
            float4 o0 = op[0], o1 = op[1];
            o0.x += acc[0] * inv; o0.y += acc[1] * inv;
            o0.z += acc[2] * inv; o0.w += acc[3] * inv;
            o1.x += acc[4] * inv; o1.y += acc[5] * inv;
            o1.z += acc[6] * inv; o1.w += acc[7] * inv;
            op[0] = o0; op[1] = o1;
        }
    }
}

// ---------------- MFMA conv: D[NNx128] = A[NNx128] @ B[128x128] + epilogue ----------------
// wave = 16 nodes x 128 channels; A-frags from global; B (transposed, padded) in LDS.
// IS1: +bias[j], store bf16 hpreb[n*128+j], accumulate exact fp32 BN stats.
// !IS1: j<64 -> pb[n*64+j] bf16 ; j>=64 -> out[n*64+j-64] = v + bias[j-64].
template<bool IS1>
__global__ __launch_bounds__(256) void conv_mfma_kernel(
    const unsigned short* __restrict__ A, const unsigned short* __restrict__ BT,
    const float* __restrict__ bias,
    unsigned short* __restrict__ outb, float* __restrict__ outf,
    float* __restrict__ sums, float* __restrict__ sumsq)
{
    __shared__ unsigned short bt[128 * 136];   // +8 pad breaks 256B-stride bank aliasing
    for (int idx = threadIdx.x; idx < 128 * 16; idx += 256) {
        int r = idx >> 4, c = idx & 15;
        ((uint4*)(bt + r * 136))[c] = ((const uint4*)(BT + r * 128))[c];
    }
    __syncthreads();
    int lane = threadIdx.x & 63;
    int wid = threadIdx.x >> 6;
    int m = lane & 15;         // A-row / B-col within frag
    int ko = lane >> 4;        // k-octet
    float s_sum[8], s_sq[8];
    if (IS1) {
#pragma unroll
        for (int t = 0; t < 8; t++) { s_sum[t] = 0.f; s_sq[t] = 0.f; }
    }
    const int tiles = (NN + 63) / 64;
    for (int tile = blockIdx.x; tile < tiles; tile += gridDim.x) {
        int n0 = tile * 64 + wid * 16;
        int mrow = n0 + m;
        int mr = mrow < NN ? mrow : NN - 1;
        const unsigned short* arow = A + (size_t)mr * 128 + ko * 8;
        bf16x8 a[4];
#pragma unroll
        for (int ks = 0; ks < 4; ks++) a[ks] = *(const bf16x8*)(arow + ks * 32);
#pragma unroll
        for (int jg = 0; jg < 8; jg++) {
            f32x4 acc = {0.f, 0.f, 0.f, 0.f};
            const unsigned short* brow = bt + (jg * 16 + m) * 136 + ko * 8;
#pragma unroll
            for (int ks = 0; ks < 4; ks++) {
                bf16x8 b = *(const bf16x8*)(brow + ks * 32);
                acc = __builtin_amdgcn_mfma_f32_16x16x32_bf16(a[ks], b, acc, 0, 0, 0);
            }
            int j = jg * 16 + m;
#pragma unroll
            for (int r = 0; r < 4; r++) {
                int n = n0 + ko * 4 + r;
                if (n < NN) {
                    float v = acc[r];
                    if (IS1) {
                        v += bias[j];
                        outb[(size_t)n * 128 + j] = f2bf(v);
                        s_sum[jg] += v;
                        s_sq[jg] += v * v;
                    } else {
                        if (j < 64) outb[(size_t)n * 64 + j] = f2bf(v);
                        else        outf[(size_t)n * 64 + (j - 64)] = v + bias[j - 64];
                    }
                }
            }
        }
    }
    if (IS1) {
#pragma unroll
        for (int jg = 0; jg < 8; jg++) {
            float v = s_sum[jg];
            v += __shfl_xor(v, 16, 64);
            v += __shfl_xor(v, 32, 64);
            float w = s_sq[jg];
            w += __shfl_xor(w, 16, 64);
            w += __shfl_xor(w, 32, 64);
            if (lane < 16) {
                atomicAdd(&sums[jg * 16 + lane], v);
                atomicAdd(&sumsq[jg * 16 + lane], w);
            }
        }
    }
}

// ---------------- BN stats -> scale/shift ----------------
__global__ void bnstat_kernel(const float* __restrict__ sums, const float* __restrict__ sumsq,
                              const float* __restrict__ gamma, const float* __restrict__ beta,
                              float* __restrict__ scale, float* __restrict__ shift) {
    int c = threadIdx.x;
    if (c < HID) {
        float inv_n = 1.0f / (float)NN;
        float mu = sums[c] * inv_n;
        float var = sumsq[c] * inv_n - mu * mu;
        float s = gamma[c] * rsqrtf(var + 1e-5f);
        scale[c] = s;
        shift[c] = beta[c] - mu * s;
    }
}

// ---------------- bn+relu apply: h = relu(bn(hpreb)) bf16 -> A1 ----------------
__global__ void bnapply_kernel(const unsigned short* __restrict__ hpreb,
                               const float* __restrict__ scale, const float* __restrict__ shift,
                               unsigned short* __restrict__ A1) {
    int idx = blockIdx.x * 256 + threadIdx.x;   // NN*16 octet slots
    if (idx >= NN * 16) return;
    int q = idx & 15;
    int j0 = q * 8;
    uint4 v = ((const uint4*)hpreb)[idx];
    float f[8];
    f[0] = bflo(v.x); f[1] = bfhi(v.x);
    f[2] = bflo(v.y); f[3] = bfhi(v.y);
    f[4] = bflo(v.z); f[5] = bfhi(v.z);
    f[6] = bflo(v.w); f[7] = bfhi(v.w);
#pragma unroll
    for (int t = 0; t < 8; t++) {
        float h = f[t] * scale[j0 + t] + shift[j0 + t];
        f[t] = h > 0.f ? h : 0.f;
    }
    uint4 o;
    o.x = (unsigned)f2bf(f[0]) | ((unsigned)f2bf(f[1]) << 16);
    o.y = (unsigned)f2bf(f[2]) | ((unsigned)f2bf(f[3]) << 16);
    o.z = (unsigned)f2bf(f[4]) | ((unsigned)f2bf(f[5]) << 16);
    o.w = (unsigned)f2bf(f[6]) | ((unsigned)f2bf(f[7]) << 16);
    ((uint4*)A1)[idx] = o;
}

extern "C" void kernel_launch(void* const* d_in, const int* in_sizes, int n_in,
                              void* d_out, int out_size, void* d_ws, size_t ws_size,
                              hipStream_t stream) {
    const float* x     = (const float*)d_in[0];
    const int*   ei    = (const int*)d_in[1];
    const float* W1l   = (const float*)d_in[2];
    const float* b1    = (const float*)d_in[3];
    const float* W1r   = (const float*)d_in[4];
    const float* gamma = (const float*)d_in[5];
    const float* beta  = (const float*)d_in[6];
    const float* W2l   = (const float*)d_in[7];
    const float* b2    = (const float*)d_in[8];
    const float* W2r   = (const float*)d_in[9];
    float* out = (float*)d_out;

    // workspace layout (~29.3 MB, proven-safe budget)
    char* wsb = (char*)d_ws;
    int*   cnt    = (int*)wsb;                                  // NN
    int*   startp = cnt + NN;                                   // NN
    int*   bsum   = cnt + 2 * NN;                               // 256
    int*   boff   = bsum + 256;                                 // 256
    int*   perm   = boff + 256;                                 // NE
    unsigned short* A1    = (unsigned short*)(perm + NE);       // NN*128 bf16 (12.8 MB)
    unsigned short* hpreb = A1 + (size_t)NN * 128;              // NN*128 bf16 (12.8 MB); reused as pb
    unsigned short* BT1   = hpreb + (size_t)NN * 128;           // 128*128 bf16
    unsigned short* BT2   = BT1 + 128 * 128;                    // 128*128 bf16
    float* sums  = (float*)(BT2 + 128 * 128);                   // 128
    float* sumsq = sums + 128;                                  // 128
    float* scale = sums + 256;                                  // 128
    float* shift = sums + 384;                                  // 128

    const int* srcp = ei;
    const int* dstp = ei + NE;

    hipMemsetAsync(cnt, 0, sizeof(int) * NN, stream);
    hipMemsetAsync(sums, 0, sizeof(float) * 256, stream);

    const int EB = (NE + 255) / 256;
    const int SB = (NN + 255) / 256;
    const int GB = (NN * 64 + 255) / 256;   // one wave per node
    const int XB = (NN * 16 + 255) / 256;

    hist_kernel<<<EB, 256, 0, stream>>>(dstp, cnt);
    scan1_kernel<<<SB, 256, 0, stream>>>(cnt, startp, bsum);
    scan2_kernel<<<1, 256, 0, stream>>>(bsum, boff, SB);
    scan3_kernel<<<SB, 256, 0, stream>>>(startp, boff, cnt);
    scatter_kernel<<<EB, 256, 0, stream>>>(srcp, dstp, cnt, perm);

    wprep_kernel<<<64, 256, 0, stream>>>(W1l, W1r, W2l, W2r, BT1, BT2);
    x2bf_kernel<<<XB, 256, 0, stream>>>(x, A1);

    // agg1: gather A1 x-half (cols 64:128) -> bf16 mean into A1 cols 0:64
    agg_gather_b<0><<<GB, 256, 0, stream>>>(A1, 128, 64, startp, perm, A1, 128, 0, nullptr);
    // conv1: hpre = A1 @ [W1l;W1r] + b1 ; bf16 store + exact fp32 BN stats
    conv_mfma_kernel<true><<<256, 256, 0, stream>>>(A1, BT1, b1, hpreb, nullptr, sums, sumsq);
    bnstat_kernel<<<1, 128, 0, stream>>>(sums, sumsq, gamma, beta, scale, shift);
    // h = relu(bn(hpreb)) -> A1
    bnapply_kernel<<<XB, 256, 0, stream>>>(hpreb, scale, shift, A1);
    // conv2: [p | self] = A1 @ [W2l|W2r] ; p bf16 -> hpreb(=pb), self+b2 -> out
    conv_mfma_kernel<false><<<256, 256, 0, stream>>>(A1, BT2, b2, hpreb, out, nullptr, nullptr);
    // agg2: gather pb rows -> out += mean
    agg_gather_b<1><<<GB, 256, 0, stream>>>(hpreb, 64, 0, startp, perm, nullptr, 0, 0, out);
}

// Round 8
// 302.056 us; speedup vs baseline: 1.9361x; 1.0151x over previous
//
#include <hip/hip_runtime.h>

#define NN 50000
#define NE 800000
#define HID 128
#define OUTD 64

typedef __attribute__((ext_vector_type(8))) short bf16x8;
typedef __attribute__((ext_vector_type(4))) float f32x4;

static __device__ __forceinline__ unsigned short f2bf(float f) {
    unsigned u = __float_as_uint(f);
    unsigned r = (u + 0x7FFFu + ((u >> 16) & 1u)) >> 16;   // RNE
    return (unsigned short)r;
}
static __device__ __forceinline__ float bflo(unsigned u) { return __uint_as_float(u << 16); }
static __device__ __forceinline__ float bfhi(unsigned u) { return __uint_as_float(u & 0xffff0000u); }

// ---------------- CSR build ----------------
__global__ void hist_kernel(const int* __restrict__ dst, int* __restrict__ cnt) {
    int e = blockIdx.x * blockDim.x + threadIdx.x;
    if (e < NE) atomicAdd(&cnt[dst[e]], 1);
}

__global__ void scan1_kernel(const int* __restrict__ cnt, int* __restrict__ excl,
                             int* __restrict__ bsum) {
    __shared__ int tmp[256];
    int tid = threadIdx.x;
    int i = blockIdx.x * 256 + tid;
    int v = (i < NN) ? cnt[i] : 0;
    tmp[tid] = v;
    __syncthreads();
    for (int off = 1; off < 256; off <<= 1) {
        int t = (tid >= off) ? tmp[tid - off] : 0;
        __syncthreads();
        tmp[tid] += t;
        __syncthreads();
    }
    if (i < NN) excl[i] = tmp[tid] - v;
    if (tid == 255) bsum[blockIdx.x] = tmp[255];
}

__global__ void scan2_kernel(int* __restrict__ bsum, int* __restrict__ boff, int nb) {
    __shared__ int tmp[256];
    int tid = threadIdx.x;
    int v = (tid < nb) ? bsum[tid] : 0;
    tmp[tid] = v;
    __syncthreads();
    for (int off = 1; off < 256; off <<= 1) {
        int t = (tid >= off) ? tmp[tid - off] : 0;
        __syncthreads();
        tmp[tid] += t;
        __syncthreads();
    }
    if (tid < nb) boff[tid] = tmp[tid] - v;
}

__global__ void scan3_kernel(int* __restrict__ excl, const int* __restrict__ boff,
                             int* __restrict__ next) {
    int i = blockIdx.x * 256 + threadIdx.x;
    if (i < NN) {
        int s = excl[i] + boff[blockIdx.x];
        excl[i] = s;
        next[i] = s;
    }
}

__global__ void scatter_kernel(const int* __restrict__ src, const int* __restrict__ dst,
                               int* __restrict__ next, int* __restrict__ perm) {
    int e = blockIdx.x * blockDim.x + threadIdx.x;
    if (e < NE) {
        int pos = atomicAdd(&next[dst[e]], 1);
        perm[pos] = src[e];
    }
}

// ---------------- weight prep: BT1[j][k], BT2[j][k] bf16 (transposed, k-contig) --------
__global__ void wprep_kernel(const float* __restrict__ W1l, const float* __restrict__ W1r,
                             const float* __restrict__ W2l, const float* __restrict__ W2r,
                             unsigned short* __restrict__ BT1, unsigned short* __restrict__ BT2) {
    int idx = blockIdx.x * 256 + threadIdx.x;
    if (idx >= 128 * 128) return;
    int j = idx >> 7, k = idx & 127;
    float v1 = (k < 64) ? W1l[k * HID + j] : W1r[(k - 64) * HID + j];
    BT1[j * 128 + k] = f2bf(v1);
    float v2 = (j < 64) ? W2l[k * OUTD + j] : W2r[k * OUTD + (j - 64)];
    BT2[j * 128 + k] = f2bf(v2);
}

// ---------------- x -> bf16 into A1 cols [64:128) ----------------
__global__ void x2bf_kernel(const float* __restrict__ x, unsigned short* __restrict__ A1) {
    int idx = blockIdx.x * 256 + threadIdx.x;   // NN*16 float4 slots
    if (idx >= NN * 16) return;
    int n = idx >> 4, q = idx & 15;
    float4 v = ((const float4*)x)[idx];
    ushort4 o;
    o.x = f2bf(v.x); o.y = f2bf(v.y); o.z = f2bf(v.z); o.w = f2bf(v.w);
    *(ushort4*)(A1 + (size_t)n * 128 + 64 + q * 4) = o;
}

// ---------------- gather-aggregate over bf16 rows, one wave per node --------
// MODE 0: store bf16 mean into outb row; MODE 1: outf[n*64+c] += mean (fp32)
template<int MODE>
__global__ __launch_bounds__(256) void agg_gather_b(
    const unsigned short* __restrict__ feat, int fstride, int foff,
    const int* __restrict__ start, const int* __restrict__ perm,
    unsigned short* __restrict__ outb, int ostride, int ooff,
    float* __restrict__ outf)
{
    int wave = (blockIdx.x * blockDim.x + threadIdx.x) >> 6;
    if (wave >= NN) return;
    int lane = threadIdx.x & 63;
    int g = lane >> 3;        // 8 edge groups
    int q = lane & 7;         // 8 bf16 per slot
    int rs = start[wave];
    int re = (wave == NN - 1) ? NE : start[wave + 1];
    float acc[8];
#pragma unroll
    for (int t = 0; t < 8; t++) acc[t] = 0.f;
    for (int i = rs + g; i < re; i += 8) {
        int s = perm[i];
        uint4 v = *(const uint4*)(feat + (size_t)s * fstride + foff + q * 8);
        acc[0] += bflo(v.x); acc[1] += bfhi(v.x);
        acc[2] += bflo(v.y); acc[3] += bfhi(v.y);
        acc[4] += bflo(v.z); acc[5] += bfhi(v.z);
        acc[6] += bflo(v.w); acc[7] += bfhi(v.w);
    }
#pragma unroll
    for (int t = 0; t < 8; t++) {
        acc[t] += __shfl_xor(acc[t], 8, 64);
        acc[t] += __shfl_xor(acc[t], 16, 64);
        acc[t] += __shfl_xor(acc[t], 32, 64);
    }
    if (g == 0) {
        int cnt = re - rs;
        float inv = (cnt > 0) ? (1.0f / (float)cnt) : 0.f;
        if (MODE == 0) {
            uint4 o;
            o.x = (unsigned)f2bf(acc[0] * inv) | ((unsigned)f2bf(acc[1] * inv) << 16);
            o.y = (unsigned)f2bf(acc[2] * inv) | ((unsigned)f2bf(acc[3] * inv) << 16);
            o.z = (unsigned)f2bf(acc[4] * inv) | ((unsigned)f2bf(acc[5] * inv) << 16);
            o.w = (unsigned)f2bf(acc[6] * inv) | ((unsigned)f2bf(acc[7] * inv) << 16);
            *(uint4*)(outb + (size_t)wave * ostride + ooff + q * 8) = o;
        } else {
            float4* op = (float4*)(outf + (size_t)wave * 64 + q * 8);
            float4 o0 = op[0], o1 = op[1];
            o0.x += acc[0] * inv; o0.y += acc[1] * inv;
            o0.z += acc[2] * inv; o0.w += acc[3] * inv;
            o1.x += acc[4] * inv; o1.y += acc[5] * inv;
            o1.z += acc[6] * inv; o1.w += acc[7] * inv;
            op[0] = o0; op[1] = o1;
        }
    }
}

// ---------------- MFMA conv v2: B in registers, no hot-loop LDS ----------------
// Job = (16-node tile) x (64-wide j-half). Wave preloads 16 B-frags (64 VGPR).
// IS1: +bias[j], bf16 store to outb[n*128+j], fp32 BN stats (shfl+LDS+atomic).
// !IS1: jh=0 -> pb[n*64+j] bf16 ; jh=1 -> out[n*64+j-64] = v + b2[j-64].
template<bool IS1>
__global__ __launch_bounds__(256) void conv_mfma_kernel(
    const unsigned short* __restrict__ A, const unsigned short* __restrict__ BT,
    const float* __restrict__ bias,
    unsigned short* __restrict__ outb, float* __restrict__ outf,
    float* __restrict__ sums, float* __restrict__ sumsq)
{
    __shared__ float red_s[4][128];
    __shared__ float red_q[4][128];
    int tid = threadIdx.x;
    int wid = tid >> 6, lane = tid & 63;
    int m = lane & 15, ko = lane >> 4;
    int gw = blockIdx.x * 4 + wid;
    int jh = gw & 1;                       // j-half this wave owns
    // preload B fragments for this j-half (16 x bf16x8 = 64 VGPRs)
    bf16x8 b[4][4];
    const unsigned short* bbase = BT + (size_t)(jh * 64 + m) * 128 + ko * 8;
#pragma unroll
    for (int jg = 0; jg < 4; jg++)
#pragma unroll
        for (int ks = 0; ks < 4; ks++)
            b[jg][ks] = *(const bf16x8*)(bbase + jg * 16 * 128 + ks * 32);
    float bj[4];
#pragma unroll
    for (int jg = 0; jg < 4; jg++)
        bj[jg] = IS1 ? bias[jh * 64 + jg * 16 + m] : (jh ? bias[jg * 16 + m] : 0.f);
    float s_sum[4] = {0.f, 0.f, 0.f, 0.f}, s_sq[4] = {0.f, 0.f, 0.f, 0.f};
    const int tiles = NN / 16;             // 3125, exact
    int stride = (gridDim.x * 4) >> 1;
    for (int tile = gw >> 1; tile < tiles; tile += stride) {
        int n0 = tile * 16;
        const unsigned short* arow = A + (size_t)(n0 + m) * 128 + ko * 8;
        bf16x8 a[4];
#pragma unroll
        for (int ks = 0; ks < 4; ks++) a[ks] = *(const bf16x8*)(arow + ks * 32);
#pragma unroll
        for (int jg = 0; jg < 4; jg++) {
            f32x4 acc = {0.f, 0.f, 0.f, 0.f};
#pragma unroll
            for (int ks = 0; ks < 4; ks++)
                acc = __builtin_amdgcn_mfma_f32_16x16x32_bf16(a[ks], b[jg][ks], acc, 0, 0, 0);
            int j = jh * 64 + jg * 16 + m;
#pragma unroll
            for (int r = 0; r < 4; r++) {
                int n = n0 + ko * 4 + r;
                float v = acc[r];
                if (IS1) {
                    v += bj[jg];
                    outb[(size_t)n * 128 + j] = f2bf(v);
                    s_sum[jg] += v;
                    s_sq[jg] += v * v;
                } else {
                    if (jh == 0) outb[(size_t)n * 64 + j] = f2bf(v);
                    else         outf[(size_t)n * 64 + (j - 64)] = v + bj[jg];
                }
            }
        }
    }
    if (IS1) {
        for (int i = tid; i < 512; i += 256) {
            ((float*)red_s)[i] = 0.f;
            ((float*)red_q)[i] = 0.f;
        }
        __syncthreads();
#pragma unroll
        for (int jg = 0; jg < 4; jg++) {
            float v = s_sum[jg];
            v += __shfl_xor(v, 16, 64);
            v += __shfl_xor(v, 32, 64);
            float w = s_sq[jg];
            w += __shfl_xor(w, 16, 64);
            w += __shfl_xor(w, 32, 64);
            if (lane < 16) {
                red_s[wid][jh * 64 + jg * 16 + lane] = v;
                red_q[wid][jh * 64 + jg * 16 + lane] = w;
            }
        }
        __syncthreads();
        if (tid < 128) {
            float v = red_s[0][tid] + red_s[1][tid] + red_s[2][tid] + red_s[3][tid];
            atomicAdd(&sums[tid], v);
        } else {
            int j = tid - 128;
            float v = red_q[0][j] + red_q[1][j] + red_q[2][j] + red_q[3][j];
            atomicAdd(&sumsq[j], v);
        }
    }
}

// ---------------- BN stats -> scale/shift ----------------
__global__ void bnstat_kernel(const float* __restrict__ sums, const float* __restrict__ sumsq,
                              const float* __restrict__ gamma, const float* __restrict__ beta,
                              float* __restrict__ scale, float* __restrict__ shift) {
    int c = threadIdx.x;
    if (c < HID) {
        float inv_n = 1.0f / (float)NN;
        float mu = sums[c] * inv_n;
        float var = sumsq[c] * inv_n - mu * mu;
        float s = gamma[c] * rsqrtf(var + 1e-5f);
        scale[c] = s;
        shift[c] = beta[c] - mu * s;
    }
}

// ---------------- bn+relu apply: h = relu(bn(hpreb)) bf16 -> A1 ----------------
__global__ void bnapply_kernel(const unsigned short* __restrict__ hpreb,
                               const float* __restrict__ scale, const float* __restrict__ shift,
                               unsigned short* __restrict__ A1) {
    int idx = blockIdx.x * 256 + threadIdx.x;   // NN*16 octet slots
    if (idx >= NN * 16) return;
    int q = idx & 15;
    int j0 = q * 8;
    uint4 v = ((const uint4*)hpreb)[idx];
    float f[8];
    f[0] = bflo(v.x); f[1] = bfhi(v.x);
    f[2] = bflo(v.y); f[3] = bfhi(v.y);
    f[4] = bflo(v.z); f[5] = bfhi(v.z);
    f[6] = bflo(v.w); f[7] = bfhi(v.w);
#pragma unroll
    for (int t = 0; t < 8; t++) {
        float h = f[t] * scale[j0 + t] + shift[j0 + t];
        f[t] = h > 0.f ? h : 0.f;
    }
    uint4 o;
    o.x = (unsigned)f2bf(f[0]) | ((unsigned)f2bf(f[1]) << 16);
    o.y = (unsigned)f2bf(f[2]) | ((unsigned)f2bf(f[3]) << 16);
    o.z = (unsigned)f2bf(f[4]) | ((unsigned)f2bf(f[5]) << 16);
    o.w = (unsigned)f2bf(f[6]) | ((unsigned)f2bf(f[7]) << 16);
    ((uint4*)A1)[idx] = o;
}

extern "C" void kernel_launch(void* const* d_in, const int* in_sizes, int n_in,
                              void* d_out, int out_size, void* d_ws, size_t ws_size,
                              hipStream_t stream) {
    const float* x     = (const float*)d_in[0];
    const int*   ei    = (const int*)d_in[1];
    const float* W1l   = (const float*)d_in[2];
    const float* b1    = (const float*)d_in[3];
    const float* W1r   = (const float*)d_in[4];
    const float* gamma = (const float*)d_in[5];
    const float* beta  = (const float*)d_in[6];
    const float* W2l   = (const float*)d_in[7];
    const float* b2    = (const float*)d_in[8];
    const float* W2r   = (const float*)d_in[9];
    float* out = (float*)d_out;

    // workspace layout (~29.3 MB, proven-safe budget)
    char* wsb = (char*)d_ws;
    int*   cnt    = (int*)wsb;                                  // NN
    int*   startp = cnt + NN;                                   // NN
    int*   bsum   = cnt + 2 * NN;                               // 256
    int*   boff   = bsum + 256;                                 // 256
    int*   perm   = boff + 256;                                 // NE
    unsigned short* A1    = (unsigned short*)(perm + NE);       // NN*128 bf16
    unsigned short* hpreb = A1 + (size_t)NN * 128;              // NN*128 bf16; reused as pb
    unsigned short* BT1   = hpreb + (size_t)NN * 128;           // 128*128 bf16
    unsigned short* BT2   = BT1 + 128 * 128;                    // 128*128 bf16
    float* sums  = (float*)(BT2 + 128 * 128);                   // 128
    float* sumsq = sums + 128;                                  // 128
    float* scale = sums + 256;                                  // 128
    float* shift = sums + 384;                                  // 128

    const int* srcp = ei;
    const int* dstp = ei + NE;

    hipMemsetAsync(cnt, 0, sizeof(int) * NN, stream);
    hipMemsetAsync(sums, 0, sizeof(float) * 256, stream);

    const int EB = (NE + 255) / 256;
    const int SB = (NN + 255) / 256;
    const int GB = (NN * 64 + 255) / 256;   // one wave per node
    const int XB = (NN * 16 + 255) / 256;
    const int CB = 1563;                    // ceil(3125 tiles * 2 halves / 4 waves)

    hist_kernel<<<EB, 256, 0, stream>>>(dstp, cnt);
    scan1_kernel<<<SB, 256, 0, stream>>>(cnt, startp, bsum);
    scan2_kernel<<<1, 256, 0, stream>>>(bsum, boff, SB);
    scan3_kernel<<<SB, 256, 0, stream>>>(startp, boff, cnt);
    scatter_kernel<<<EB, 256, 0, stream>>>(srcp, dstp, cnt, perm);

    wprep_kernel<<<64, 256, 0, stream>>>(W1l, W1r, W2l, W2r, BT1, BT2);
    x2bf_kernel<<<XB, 256, 0, stream>>>(x, A1);

    // agg1: gather A1 x-half (cols 64:128) -> bf16 mean into A1 cols 0:64
    agg_gather_b<0><<<GB, 256, 0, stream>>>(A1, 128, 64, startp, perm, A1, 128, 0, nullptr);
    // conv1: hpre = A1 @ [W1l;W1r] + b1 ; bf16 store + fp32 BN stats
    conv_mfma_kernel<true><<<CB, 256, 0, stream>>>(A1, BT1, b1, hpreb, nullptr, sums, sumsq);
    bnstat_kernel<<<1, 128, 0, stream>>>(sums, sumsq, gamma, beta, scale, shift);
    // h = relu(bn(hpreb)) -> A1
    bnapply_kernel<<<XB, 256, 0, stream>>>(hpreb, scale, shift, A1);
    // conv2: [p | self] = A1 @ [W2l|W2r] ; p bf16 -> hpreb(=pb), self+b2 -> out
    conv_mfma_kernel<false><<<CB, 256, 0, stream>>>(A1, BT2, b2, hpreb, out, nullptr, nullptr);
    // agg2: gather pb rows -> out += mean
    agg_gather_b<1><<<GB, 256, 0, stream>>>(hpreb, 64, 0, startp, perm, nullptr, 0, 0, out);
}

// Round 9
// 279.807 us; speedup vs baseline: 2.0901x; 1.0795x over previous
//
#include <hip/hip_runtime.h>

#define NN 50000
#define NE 800000
#define HID 128
#define OUTD 64

typedef __attribute__((ext_vector_type(8))) short bf16x8;
typedef __attribute__((ext_vector_type(4))) float f32x4;

static __device__ __forceinline__ unsigned short f2bf(float f) {
    unsigned u = __float_as_uint(f);
    unsigned r = (u + 0x7FFFu + ((u >> 16) & 1u)) >> 16;   // RNE
    return (unsigned short)r;
}
static __device__ __forceinline__ float bflo(unsigned u) { return __uint_as_float(u << 16); }
static __device__ __forceinline__ float bfhi(unsigned u) { return __uint_as_float(u & 0xffff0000u); }

// ---------------- CSR build ----------------
__global__ void hist_kernel(const int* __restrict__ dst, int* __restrict__ cnt) {
    int e = blockIdx.x * blockDim.x + threadIdx.x;
    if (e < NE) atomicAdd(&cnt[dst[e]], 1);
}

__global__ void scan1_kernel(const int* __restrict__ cnt, int* __restrict__ excl,
                             int* __restrict__ bsum) {
    __shared__ int tmp[256];
    int tid = threadIdx.x;
    int i = blockIdx.x * 256 + tid;
    int v = (i < NN) ? cnt[i] : 0;
    tmp[tid] = v;
    __syncthreads();
    for (int off = 1; off < 256; off <<= 1) {
        int t = (tid >= off) ? tmp[tid - off] : 0;
        __syncthreads();
        tmp[tid] += t;
        __syncthreads();
    }
    if (i < NN) excl[i] = tmp[tid] - v;
    if (tid == 255) bsum[blockIdx.x] = tmp[255];
}

__global__ void scan2_kernel(int* __restrict__ bsum, int* __restrict__ boff, int nb) {
    __shared__ int tmp[256];
    int tid = threadIdx.x;
    int v = (tid < nb) ? bsum[tid] : 0;
    tmp[tid] = v;
    __syncthreads();
    for (int off = 1; off < 256; off <<= 1) {
        int t = (tid >= off) ? tmp[tid - off] : 0;
        __syncthreads();
        tmp[tid] += t;
        __syncthreads();
    }
    if (tid < nb) boff[tid] = tmp[tid] - v;
}

__global__ void scan3_kernel(int* __restrict__ excl, const int* __restrict__ boff,
                             int* __restrict__ next) {
    int i = blockIdx.x * 256 + threadIdx.x;
    if (i < NN) {
        int s = excl[i] + boff[blockIdx.x];
        excl[i] = s;
        next[i] = s;
    }
}

__global__ void scatter_kernel(const int* __restrict__ src, const int* __restrict__ dst,
                               int* __restrict__ next, int* __restrict__ perm) {
    int e = blockIdx.x * blockDim.x + threadIdx.x;
    if (e < NE) {
        int pos = atomicAdd(&next[dst[e]], 1);
        __builtin_nontemporal_store(src[e], &perm[pos]);
    }
}

// ---------------- weight prep: BT1[j][k], BT2[j][k] bf16 (transposed, k-contig) --------
__global__ void wprep_kernel(const float* __restrict__ W1l, const float* __restrict__ W1r,
                             const float* __restrict__ W2l, const float* __restrict__ W2r,
                             unsigned short* __restrict__ BT1, unsigned short* __restrict__ BT2) {
    int idx = blockIdx.x * 256 + threadIdx.x;
    if (idx >= 128 * 128) return;
    int j = idx >> 7, k = idx & 127;
    float v1 = (k < 64) ? W1l[k * HID + j] : W1r[(k - 64) * HID + j];
    BT1[j * 128 + k] = f2bf(v1);
    float v2 = (j < 64) ? W2l[k * OUTD + j] : W2r[k * OUTD + (j - 64)];
    BT2[j * 128 + k] = f2bf(v2);
}

// ---------------- x -> bf16 into A1 cols [64:128) ----------------
__global__ void x2bf_kernel(const float* __restrict__ x, unsigned short* __restrict__ A1) {
    int idx = blockIdx.x * 256 + threadIdx.x;   // NN*16 float4 slots
    if (idx >= NN * 16) return;
    int n = idx >> 4, q = idx & 15;
    float4 v = ((const float4*)x)[idx];
    ushort4 o;
    o.x = f2bf(v.x); o.y = f2bf(v.y); o.z = f2bf(v.z); o.w = f2bf(v.w);
    *(ushort4*)(A1 + (size_t)n * 128 + 64 + q * 4) = o;
}

// ---------------- gather-aggregate over bf16 rows, one wave per node --------
// MODE 0: store bf16 mean into outb row; MODE 1: outf[n*64+c] += mean (fp32)
template<int MODE>
__global__ __launch_bounds__(256) void agg_gather_b(
    const unsigned short* __restrict__ feat, int fstride, int foff,
    const int* __restrict__ start, const int* __restrict__ perm,
    unsigned short* __restrict__ outb, int ostride, int ooff,
    float* __restrict__ outf)
{
    int wave = (blockIdx.x * blockDim.x + threadIdx.x) >> 6;
    if (wave >= NN) return;
    int lane = threadIdx.x & 63;
    int g = lane >> 3;        // 8 edge groups
    int q = lane & 7;         // 8 bf16 per slot
    int rs = start[wave];
    int re = (wave == NN - 1) ? NE : start[wave + 1];
    float acc[8];
#pragma unroll
    for (int t = 0; t < 8; t++) acc[t] = 0.f;
    for (int i = rs + g; i < re; i += 8) {
        int s = perm[i];
        uint4 v = *(const uint4*)(feat + (size_t)s * fstride + foff + q * 8);
        acc[0] += bflo(v.x); acc[1] += bfhi(v.x);
        acc[2] += bflo(v.y); acc[3] += bfhi(v.y);
        acc[4] += bflo(v.z); acc[5] += bfhi(v.z);
        acc[6] += bflo(v.w); acc[7] += bfhi(v.w);
    }
#pragma unroll
    for (int t = 0; t < 8; t++) {
        acc[t] += __shfl_xor(acc[t], 8, 64);
        acc[t] += __shfl_xor(acc[t], 16, 64);
        acc[t] += __shfl_xor(acc[t], 32, 64);
    }
    if (g == 0) {
        int cnt = re - rs;
        float inv = (cnt > 0) ? (1.0f / (float)cnt) : 0.f;
        if (MODE == 0) {
            uint4 o;
            o.x = (unsigned)f2bf(acc[0] * inv) | ((unsigned)f2bf(acc[1] * inv) << 16);
            o.y = (unsigned)f2bf(acc[2] * inv) | ((unsigned)f2bf(acc[3] * inv) << 16);
            o.z = (unsigned)f2bf(acc[4] * inv) | ((unsigned)f2bf(acc[5] * inv) << 16);
            o.w = (unsigned)f2bf(acc[6] * inv) | ((unsigned)f2bf(acc[7] * inv) << 16);
            *(uint4*)(outb + (size_t)wave * ostride + ooff + q * 8) = o;
        } else {
            float4* op = (float4*)(outf + (size_t)wave * 64 + q * 8);
            float4 o0 = op[0], o1 = op[1];
            o0.x += acc[0] * inv; o0.y += acc[1] * inv;
            o0.z += acc[2] * inv; o0.w += acc[3] * inv;
            o1.x += acc[4] * inv; o1.y += acc[5] * inv;
            o1.z += acc[6] * inv; o1.w += acc[7] * inv;
            op[0] = o0; op[1] = o1;
        }
    }
}

// ---------------- MFMA conv v3: B in registers, multi-tile per wave, A prefetch -------
// Job = (16-node tile) x (64-wide j-half); 1024 waves, ~6 tiles each.
// IS1: +bias[j], bf16 store to outb[n*128+j], fp32 BN stats (shfl+LDS+atomic).
// !IS1: jh=0 -> pb[n*64+j] bf16 ; jh=1 -> out[n*64+j-64] = v + b2[j-64].
template<bool IS1>
__global__ __launch_bounds__(256) void conv_mfma_kernel(
    const unsigned short* __restrict__ A, const unsigned short* __restrict__ BT,
    const float* __restrict__ bias,
    unsigned short* __restrict__ outb, float* __restrict__ outf,
    float* __restrict__ sums, float* __restrict__ sumsq)
{
    __shared__ float red_s[4][128];
    __shared__ float red_q[4][128];
    int tid = threadIdx.x;
    int wid = tid >> 6, lane = tid & 63;
    int m = lane & 15, ko = lane >> 4;
    int gw = blockIdx.x * 4 + wid;         // 0..1023
    int jh = gw & 1;                       // j-half this wave owns
    const int TSTRIDE = 512;               // 1024 waves / 2 halves
    const int tiles = NN / 16;             // 3125, exact
    // preload B fragments for this j-half (16 x bf16x8 = 64 VGPRs)
    bf16x8 b[4][4];
    const unsigned short* bbase = BT + (size_t)(jh * 64 + m) * 128 + ko * 8;
#pragma unroll
    for (int jg = 0; jg < 4; jg++)
#pragma unroll
        for (int ks = 0; ks < 4; ks++)
            b[jg][ks] = *(const bf16x8*)(bbase + jg * 16 * 128 + ks * 32);
    float bj[4];
#pragma unroll
    for (int jg = 0; jg < 4; jg++)
        bj[jg] = IS1 ? bias[jh * 64 + jg * 16 + m] : (jh ? bias[jg * 16 + m] : 0.f);
    float s_sum[4] = {0.f, 0.f, 0.f, 0.f}, s_sq[4] = {0.f, 0.f, 0.f, 0.f};
    int tile = gw >> 1;                    // 0..511
    bf16x8 a[4];
    if (tile < tiles) {
        const unsigned short* arow = A + (size_t)(tile * 16 + m) * 128 + ko * 8;
#pragma unroll
        for (int ks = 0; ks < 4; ks++) a[ks] = *(const bf16x8*)(arow + ks * 32);
    }
    while (tile < tiles) {
        int nxt = tile + TSTRIDE;
        bf16x8 an[4];
        if (nxt < tiles) {
            const unsigned short* arow = A + (size_t)(nxt * 16 + m) * 128 + ko * 8;
#pragma unroll
            for (int ks = 0; ks < 4; ks++) an[ks] = *(const bf16x8*)(arow + ks * 32);
        }
        int n0 = tile * 16;
#pragma unroll
        for (int jg = 0; jg < 4; jg++) {
            f32x4 acc = {0.f, 0.f, 0.f, 0.f};
#pragma unroll
            for (int ks = 0; ks < 4; ks++)
                acc = __builtin_amdgcn_mfma_f32_16x16x32_bf16(a[ks], b[jg][ks], acc, 0, 0, 0);
            int j = jh * 64 + jg * 16 + m;
#pragma unroll
            for (int r = 0; r < 4; r++) {
                int n = n0 + ko * 4 + r;
                float v = acc[r];
                if (IS1) {
                    v += bj[jg];
                    outb[(size_t)n * 128 + j] = f2bf(v);
                    s_sum[jg] += v;
                    s_sq[jg] += v * v;
                } else {
                    if (jh == 0) outb[(size_t)n * 64 + j] = f2bf(v);
                    else         outf[(size_t)n * 64 + (j - 64)] = v + bj[jg];
                }
            }
        }
#pragma unroll
        for (int ks = 0; ks < 4; ks++) a[ks] = an[ks];
        tile = nxt;
    }
    if (IS1) {
        for (int i = tid; i < 512; i += 256) {
            ((float*)red_s)[i] = 0.f;
            ((float*)red_q)[i] = 0.f;
        }
        __syncthreads();
#pragma unroll
        for (int jg = 0; jg < 4; jg++) {
            float v = s_sum[jg];
            v += __shfl_xor(v, 16, 64);
            v += __shfl_xor(v, 32, 64);
            float w = s_sq[jg];
            w += __shfl_xor(w, 16, 64);
            w += __shfl_xor(w, 32, 64);
            if (lane < 16) {
                red_s[wid][jh * 64 + jg * 16 + lane] = v;
                red_q[wid][jh * 64 + jg * 16 + lane] = w;
            }
        }
        __syncthreads();
        if (tid < 128) {
            float v = red_s[0][tid] + red_s[1][tid] + red_s[2][tid] + red_s[3][tid];
            atomicAdd(&sums[tid], v);
        } else {
            int j = tid - 128;
            float v = red_q[0][j] + red_q[1][j] + red_q[2][j] + red_q[3][j];
            atomicAdd(&sumsq[j], v);
        }
    }
}

// ---------------- BN stats -> scale/shift ----------------
__global__ void bnstat_kernel(const float* __restrict__ sums, const float* __restrict__ sumsq,
                              const float* __restrict__ gamma, const float* __restrict__ beta,
                              float* __restrict__ scale, float* __restrict__ shift) {
    int c = threadIdx.x;
    if (c < HID) {
        float inv_n = 1.0f / (float)NN;
        float mu = sums[c] * inv_n;
        float var = sumsq[c] * inv_n - mu * mu;
        float s = gamma[c] * rsqrtf(var + 1e-5f);
        scale[c] = s;
        shift[c] = beta[c] - mu * s;
    }
}

// ---------------- bn+relu apply: h = relu(bn(hpreb)) bf16 -> A1 ----------------
__global__ void bnapply_kernel(const unsigned short* __restrict__ hpreb,
                               const float* __restrict__ scale, const float* __restrict__ shift,
                               unsigned short* __restrict__ A1) {
    int idx = blockIdx.x * 256 + threadIdx.x;   // NN*16 octet slots
    if (idx >= NN * 16) return;
    int q = idx & 15;
    int j0 = q * 8;
    uint4 v = ((const uint4*)hpreb)[idx];
    float f[8];
    f[0] = bflo(v.x); f[1] = bfhi(v.x);
    f[2] = bflo(v.y); f[3] = bfhi(v.y);
    f[4] = bflo(v.z); f[5] = bfhi(v.z);
    f[6] = bflo(v.w); f[7] = bfhi(v.w);
#pragma unroll
    for (int t = 0; t < 8; t++) {
        float h = f[t] * scale[j0 + t] + shift[j0 + t];
        f[t] = h > 0.f ? h : 0.f;
    }
    uint4 o;
    o.x = (unsigned)f2bf(f[0]) | ((unsigned)f2bf(f[1]) << 16);
    o.y = (unsigned)f2bf(f[2]) | ((unsigned)f2bf(f[3]) << 16);
    o.z = (unsigned)f2bf(f[4]) | ((unsigned)f2bf(f[5]) << 16);
    o.w = (unsigned)f2bf(f[6]) | ((unsigned)f2bf(f[7]) << 16);
    ((uint4*)A1)[idx] = o;
}

extern "C" void kernel_launch(void* const* d_in, const int* in_sizes, int n_in,
                              void* d_out, int out_size, void* d_ws, size_t ws_size,
                              hipStream_t stream) {
    const float* x     = (const float*)d_in[0];
    const int*   ei    = (const int*)d_in[1];
    const float* W1l   = (const float*)d_in[2];
    const float* b1    = (const float*)d_in[3];
    const float* W1r   = (const float*)d_in[4];
    const float* gamma = (const float*)d_in[5];
    const float* beta  = (const float*)d_in[6];
    const float* W2l   = (const float*)d_in[7];
    const float* b2    = (const float*)d_in[8];
    const float* W2r   = (const float*)d_in[9];
    float* out = (float*)d_out;

    // workspace layout (~29.3 MB, proven-safe budget)
    char* wsb = (char*)d_ws;
    int*   cnt    = (int*)wsb;                                  // NN
    int*   startp = cnt + NN;                                   // NN
    int*   bsum   = cnt + 2 * NN;                               // 256
    int*   boff   = bsum + 256;                                 // 256
    int*   perm   = boff + 256;                                 // NE
    unsigned short* A1    = (unsigned short*)(perm + NE);       // NN*128 bf16
    unsigned short* hpreb = A1 + (size_t)NN * 128;              // NN*128 bf16; reused as pb
    unsigned short* BT1   = hpreb + (size_t)NN * 128;           // 128*128 bf16
    unsigned short* BT2   = BT1 + 128 * 128;                    // 128*128 bf16
    float* sums  = (float*)(BT2 + 128 * 128);                   // 128
    float* sumsq = sums + 128;                                  // 128
    float* scale = sums + 256;                                  // 128
    float* shift = sums + 384;                                  // 128

    const int* srcp = ei;
    const int* dstp = ei + NE;

    hipMemsetAsync(cnt, 0, sizeof(int) * NN, stream);
    hipMemsetAsync(sums, 0, sizeof(float) * 256, stream);

    const int EB = (NE + 255) / 256;
    const int SB = (NN + 255) / 256;
    const int GB = (NN * 64 + 255) / 256;   // one wave per node
    const int XB = (NN * 16 + 255) / 256;
    const int CB = 256;                     // 1024 waves, ~6 tiles each

    hist_kernel<<<EB, 256, 0, stream>>>(dstp, cnt);
    scan1_kernel<<<SB, 256, 0, stream>>>(cnt, startp, bsum);
    scan2_kernel<<<1, 256, 0, stream>>>(bsum, boff, SB);
    scan3_kernel<<<SB, 256, 0, stream>>>(startp, boff, cnt);
    scatter_kernel<<<EB, 256, 0, stream>>>(srcp, dstp, cnt, perm);

    wprep_kernel<<<64, 256, 0, stream>>>(W1l, W1r, W2l, W2r, BT1, BT2);
    x2bf_kernel<<<XB, 256, 0, stream>>>(x, A1);

    // agg1: gather A1 x-half (cols 64:128) -> bf16 mean into A1 cols 0:64
    agg_gather_b<0><<<GB, 256, 0, stream>>>(A1, 128, 64, startp, perm, A1, 128, 0, nullptr);
    // conv1: hpre = A1 @ [W1l;W1r] + b1 ; bf16 store + fp32 BN stats
    conv_mfma_kernel<true><<<CB, 256, 0, stream>>>(A1, BT1, b1, hpreb, nullptr, sums, sumsq);
    bnstat_kernel<<<1, 128, 0, stream>>>(sums, sumsq, gamma, beta, scale, shift);
    // h = relu(bn(hpreb)) -> A1
    bnapply_kernel<<<XB, 256, 0, stream>>>(hpreb, scale, shift, A1);
    // conv2: [p | self] = A1 @ [W2l|W2r] ; p bf16 -> hpreb(=pb), self+b2 -> out
    conv_mfma_kernel<false><<<CB, 256, 0, stream>>>(A1, BT2, b2, hpreb, out, nullptr, nullptr);
    // agg2: gather pb rows -> out += mean
    agg_gather_b<1><<<GB, 256, 0, stream>>>(hpreb, 64, 0, startp, perm, nullptr, 0, 0, out);
}